// Round 13
// baseline (423.440 us; speedup 1.0000x reference)
//
#include <hip/hip_runtime.h>
#include <hip/hip_fp16.h>

#define DIM 256
#define MARGIN 2.25e-4f

typedef __bf16 bf8v __attribute__((ext_vector_type(8)));
typedef float f4v __attribute__((ext_vector_type(4)));
typedef unsigned int u32x4 __attribute__((ext_vector_type(4)));

__device__ inline unsigned short f2bf(float x) {
    unsigned u = __float_as_uint(x);
    u += 0x7fffu + ((u >> 16) & 1u);   // RNE
    return (unsigned short)(u >> 16);
}

// ---------------- fused prep ----------------
__global__ __launch_bounds__(256) void k_prep(const float* __restrict__ z,
                                              const float* __restrict__ emb,
                                              float* __restrict__ zf,
                                              unsigned short* __restrict__ zb,
                                              unsigned short* __restrict__ eb,
                                              float* __restrict__ enorm,
                                              float* __restrict__ out_loss) {
    const int bx = blockIdx.x;
    if (bx < 2048) {
        __shared__ float tt[32][33];
        const int hw0 = (bx & 31) * 32;
        const int d0  = ((bx >> 5) & 7) * 32;
        const int b   = bx >> 8;
        const int tx = threadIdx.x & 31, ty = threadIdx.x >> 5;
#pragma unroll
        for (int i = 0; i < 4; i++) {
            const int d = d0 + ty + 8 * i;
            tt[ty + 8 * i][tx] = z[(b * 256 + d) * 1024 + hw0 + tx];
        }
        __syncthreads();
#pragma unroll
        for (int i = 0; i < 4; i++) {
            const int hw = hw0 + ty + 8 * i;
            const float v = tt[tx][ty + 8 * i];
            const size_t o = (size_t)(b * 1024 + hw) * DIM + d0 + tx;
            zf[o] = v;
            zb[o] = f2bf(v);
        }
    } else if (bx < 6144) {
        const int s = bx - 2048;
        const int wave = threadIdx.x >> 6, lane = threadIdx.x & 63;
        const int row = s * 4 + wave;
        const float4 v = *(const float4*)(emb + (size_t)row * DIM + lane * 4);
        ushort4 o;
        o.x = f2bf(v.x); o.y = f2bf(v.y); o.z = f2bf(v.z); o.w = f2bf(v.w);
        *(ushort4*)(eb + (size_t)row * DIM + lane * 4) = o;
        float ss = v.x * v.x + v.y * v.y + v.z * v.z + v.w * v.w;
#pragma unroll
        for (int m = 1; m < 64; m <<= 1) ss += __shfl_xor(ss, m, 64);
        if (lane == 0) enorm[row] = ss;
    } else {
        if (threadIdx.x == 0) out_loss[0] = 0.f;
    }
}

// ---------------- bf16 MFMA scoring: 64-row A in LDS (swizzled), B from L2, 5 blocks/CU --------
// LDS exactly 32 KB (epilogue staging aliases As) -> 5 blocks/CU.
// Group g = by*16 + wc*4 + (m15>>2): codes by*256 + wc*64 + ct*16 + (m15>>2)*4 + l
__global__ __launch_bounds__(256, 5) void k_score(
        const unsigned short* __restrict__ zb, const unsigned short* __restrict__ eb,
        const float* __restrict__ enorm, unsigned short* __restrict__ pvalh) {
    __shared__ unsigned short As[64 * 256];   // 32 KB; reused as sm[64*16] in epilogue
    const int rx = blockIdx.x & 127;
    const int by = blockIdx.x >> 7;
    const int row0 = rx * 64;
    const int col0 = by * 256;
    const int t = threadIdx.x;
    const int lane = t & 63, wc = t >> 6;
    const int q = lane >> 4, m15 = lane & 15;

#pragma unroll
    for (int j = 0; j < 8; j++) {
        const int id = j * 256 + t;
        const int r = id >> 5, sl = id & 31;
        const int c = sl ^ (r & 15);
        __builtin_amdgcn_global_load_lds(
            (const __attribute__((address_space(1))) void*)(zb + (size_t)(row0 + r) * DIM + c * 8),
            (__attribute__((address_space(3))) void*)((char*)As + id * 16), 16, 0, 0);
    }
    __syncthreads();

    f4v acc[4][4];
#pragma unroll
    for (int rt = 0; rt < 4; rt++)
#pragma unroll
        for (int ct = 0; ct < 4; ct++) acc[rt][ct] = (f4v){0.f, 0.f, 0.f, 0.f};

    const unsigned short* brow = eb + (size_t)(col0 + wc * 64 + m15) * DIM + q * 8;

#pragma unroll
    for (int kk = 0; kk < 8; kk++) {
        bf8v af[4], bfv[4];
#pragma unroll
        for (int rt = 0; rt < 4; rt++) {
            const int r = rt * 16 + m15;
            const int slot = (kk * 4 + q) ^ m15;
            af[rt] = *(const bf8v*)&As[r * 256 + slot * 8];
        }
#pragma unroll
        for (int ct = 0; ct < 4; ct++)
            bfv[ct] = *(const bf8v*)(brow + (size_t)ct * 16 * DIM + kk * 32);
#pragma unroll
        for (int rt = 0; rt < 4; rt++)
#pragma unroll
            for (int ct = 0; ct < 4; ct++)
                acc[rt][ct] = __builtin_amdgcn_mfma_f32_16x16x32_bf16(af[rt], bfv[ct], acc[rt][ct], 0, 0, 0);
    }

    // compute all group-mins into registers (no LDS use)
    float en_l[4];
#pragma unroll
    for (int ct = 0; ct < 4; ct++) en_l[ct] = enorm[col0 + wc * 64 + ct * 16 + m15];
    float svr[4][4];
#pragma unroll
    for (int rt = 0; rt < 4; rt++) {
#pragma unroll
        for (int j = 0; j < 4; j++) {
            float s = fmaf(-2.f, acc[rt][0][j], en_l[0]);
#pragma unroll
            for (int ct = 1; ct < 4; ct++)
                s = fminf(s, fmaf(-2.f, acc[rt][ct][j], en_l[ct]));
            svr[rt][j] = s;
        }
#pragma unroll
        for (int m = 1; m <= 2; m <<= 1)
#pragma unroll
            for (int j = 0; j < 4; j++)
                svr[rt][j] = fminf(svr[rt][j], __shfl_xor(svr[rt][j], m, 64));
    }

    // epilogue staging: alias As as sm[64][16] (all ds_reads of As are done; barrier first)
    __syncthreads();
    unsigned short* sm = As;
    const int gsl = wc * 4 + (m15 >> 2);
    if ((m15 & 3) == 0) {
#pragma unroll
        for (int rt = 0; rt < 4; rt++) {
            const int rl = rt * 16 + q * 4;
#pragma unroll
            for (int j = 0; j < 4; j++)
                sm[(rl + j) * 16 + gsl] = __half_as_ushort(__float2half_rn(svr[rt][j]));
        }
    }
    __syncthreads();
    if (t < 128) {
        const u32x4 v = *(const u32x4*)&sm[t * 8];
        __builtin_nontemporal_store(v,
            (u32x4*)&pvalh[(size_t)(row0 + (t >> 1)) * 1024 + by * 16 + (t & 1) * 8]);
    }
}

// ---------------- select: wave-per-row flag + exact fp32 rescore + argmin ----------------
__global__ __launch_bounds__(256) void k_select(
        const float* __restrict__ zf, const float* __restrict__ emb,
        const float* __restrict__ enorm, const unsigned short* __restrict__ pvalh,
        int* __restrict__ idxi, float* __restrict__ out_idx) {
    const int w = threadIdx.x >> 6, lane = threadIdx.x & 63;
    const int row = blockIdx.x * 4 + w;
    __shared__ float zs[4][256];
    __shared__ int lcnt[4];
    __shared__ short list[4][256];

    // z row into LDS + row norm (order-safe: enorm < half-ulp(zn) -> uniform grid shift)
    const float4 zr = *(const float4*)(zf + (size_t)row * DIM + lane * 4);
    *(float4*)&zs[w][lane * 4] = zr;
    float zn = zr.x * zr.x + zr.y * zr.y + zr.z * zr.z + zr.w * zr.w;
#pragma unroll
    for (int m = 1; m < 64; m <<= 1) zn += __shfl_xor(zn, m, 64);
    if (lane == 0) lcnt[w] = 0;

    // group-mins: 16 halves per lane
    const unsigned short* p = pvalh + (size_t)row * 1024;
    const u32x4 u0 = __builtin_nontemporal_load((const u32x4*)(p + lane * 8));
    const u32x4 u1 = __builtin_nontemporal_load((const u32x4*)(p + 512 + lane * 8));
    const __half* h0 = (const __half*)&u0;
    const __half* h1 = (const __half*)&u1;
    float v[16];
    float mn = 3.0e38f;
#pragma unroll
    for (int k = 0; k < 8; k++) {
        v[k] = __half2float(h0[k]);
        v[8 + k] = __half2float(h1[k]);
        mn = fminf(mn, fminf(v[k], v[8 + k]));
    }
#pragma unroll
    for (int m = 1; m < 64; m <<= 1) mn = fminf(mn, __shfl_xor(mn, m, 64));
    const float g = mn + MARGIN;
#pragma unroll
    for (int k = 0; k < 8; k++) {
        if (v[k] <= g) {
            const int pos = atomicAdd(&lcnt[w], 1);
            if (pos < 256) list[w][pos] = (short)(lane * 8 + k);
        }
        if (v[8 + k] <= g) {
            const int pos = atomicAdd(&lcnt[w], 1);
            if (pos < 256) list[w][pos] = (short)(512 + lane * 8 + k);
        }
    }
    const int n = min(lcnt[w], 256);

    // exact fp32 rescore: 4 codes in parallel (16 lanes/code), 4 sub-rounds per 16-code group
    const int codei = lane >> 4, lane16 = lane & 15;
    float bv = 3.0e38f;
    int bi = 0x7fffffff;
    const float* zp = &zs[w][lane16 * 16];
    for (int i = 0; i < n; i++) {
        const int gg = list[w][i];
        const int cbase = ((gg >> 4) << 8) + (((gg >> 2) & 3) << 6) + ((gg & 3) << 2);
#pragma unroll
        for (int sub = 0; sub < 4; sub++) {
            const int ci = sub * 4 + codei;
            const int code = cbase + ((ci >> 2) << 4) + (ci & 3);
            const float* ep = emb + (size_t)code * DIM + lane16 * 16;
            float d = 0.f;
#pragma unroll
            for (int k = 0; k < 16; k += 4) {
                const float4 ev = *(const float4*)(ep + k);
                const float4 zv4 = *(const float4*)(zp + k);
                d = fmaf(zv4.x, ev.x, d);
                d = fmaf(zv4.y, ev.y, d);
                d = fmaf(zv4.z, ev.z, d);
                d = fmaf(zv4.w, ev.w, d);
            }
#pragma unroll
            for (int m = 1; m <= 8; m <<= 1) d += __shfl_xor(d, m, 64);
            if (lane16 == 0) {
                const float tt = zn + enorm[code];
                const float s = tt - 2.0f * d;   // exact fp32 semantics
                if (s < bv || (s == bv && code < bi)) { bv = s; bi = code; }
            }
        }
    }
    // combine the 4 writer lanes (others hold +inf)
#pragma unroll
    for (int m = 1; m < 64; m <<= 1) {
        const float ov = __shfl_xor(bv, m, 64);
        const int oi = __shfl_xor(bi, m, 64);
        if (ov < bv || (ov == bv && oi < bi)) { bv = ov; bi = oi; }
    }
    if (lane == 0) {
        idxi[row] = bi;
        out_idx[row] = (float)bi;
    }
}

// ---------------- gather z_q (NCHW) + fused loss (atomicAdd) ----------------
__global__ __launch_bounds__(256) void k_gather(const float* __restrict__ emb,
                                                const float* __restrict__ zf,
                                                const int* __restrict__ idxi,
                                                float* __restrict__ zq,
                                                float* __restrict__ out_loss) {
    __shared__ float t[32][33];
    const int hw0 = blockIdx.x * 32;
    const int c0  = blockIdx.y * 32;
    const int b   = blockIdx.z;
    const int tx = threadIdx.x & 31, ty = threadIdx.x >> 5;
    float lsum = 0.f;
#pragma unroll
    for (int i = 0; i < 4; i++) {
        const int hh = ty + 8 * i;
        const int n = b * 1024 + hw0 + hh;
        const int id = idxi[n];
        const float q = emb[(size_t)id * DIM + c0 + tx];
        const float zv = zf[(size_t)n * DIM + c0 + tx];
        const float d = q - zv;
        lsum += d * d;
        t[hh][tx] = q;
    }
    __syncthreads();
#pragma unroll
    for (int i = 0; i < 4; i++) {
        const int c = c0 + ty + 8 * i;
        zq[(size_t)(b * 256 + c) * 1024 + hw0 + tx] = t[tx][ty + 8 * i];
    }
#pragma unroll
    for (int m = 1; m < 64; m <<= 1) lsum += __shfl_xor(lsum, m, 64);
    __shared__ float wsum[4];
    const int lane = threadIdx.x & 63, w = threadIdx.x >> 6;
    if (lane == 0) wsum[w] = lsum;
    __syncthreads();
    if (threadIdx.x == 0) {
        const float total = wsum[0] + wsum[1] + wsum[2] + wsum[3];
        atomicAdd(out_loss, total * (1.25f / 2097152.0f));
    }
}

extern "C" void kernel_launch(void* const* d_in, const int* in_sizes, int n_in,
                              void* d_out, int out_size, void* d_ws, size_t ws_size,
                              hipStream_t stream) {
    const float* z   = (const float*)d_in[0];   // [8,256,32,32]
    const float* emb = (const float*)d_in[1];   // [16384,256]
    float* out = (float*)d_out;
    float* ws  = (float*)d_ws;

    // ws layout (float-slot offsets):
    float*          zf    = ws;                                   // 2,097,152  (8 MB)
    unsigned short* pvalh = (unsigned short*)(ws + 2097152);      // 8M halves  (16 MB)
    unsigned short* zb    = (unsigned short*)(ws + 6291456);      // 2M halves  (4 MB)
    unsigned short* eb    = (unsigned short*)(ws + 7340032);      // 4M halves  (8 MB)
    float*          enorm = ws + 9437184;                         // 16,384
    int*            idxi  = (int*)(ws + 9453568);                 // 8,192
    // total ≈ 37.9 MB

    float* zq       = out;                   // [8,256,32,32] NCHW
    float* out_loss = out + 2097152;         // scalar
    float* out_idx  = out + 2097153;         // [8192] as float32

    k_prep<<<dim3(6145), 256, 0, stream>>>(z, emb, zf, zb, eb, enorm, out_loss);
    k_score<<<dim3(8192), 256, 0, stream>>>(zb, eb, enorm, pvalh);
    k_select<<<dim3(2048), 256, 0, stream>>>(zf, emb, enorm, pvalh, idxi, out_idx);
    k_gather<<<dim3(32, 8, 8), 256, 0, stream>>>(emb, zf, idxi, zq, out_loss);
}

// Round 14
// 281.629 us; speedup vs baseline: 1.5035x; 1.5035x over previous
//
#include <hip/hip_runtime.h>
#include <hip/hip_fp16.h>

#define DIM 256
#define MARGIN 2.25e-4f

typedef __bf16 bf8v __attribute__((ext_vector_type(8)));
typedef float f4v __attribute__((ext_vector_type(4)));
typedef unsigned int u32x4 __attribute__((ext_vector_type(4)));

__device__ inline unsigned short f2bf(float x) {
    unsigned u = __float_as_uint(x);
    u += 0x7fffu + ((u >> 16) & 1u);   // RNE
    return (unsigned short)(u >> 16);
}

// ---------------- fused prep ----------------
__global__ __launch_bounds__(256) void k_prep(const float* __restrict__ z,
                                              const float* __restrict__ emb,
                                              float* __restrict__ zf,
                                              unsigned short* __restrict__ zb,
                                              unsigned short* __restrict__ eb,
                                              float* __restrict__ enorm,
                                              float* __restrict__ out_loss) {
    const int bx = blockIdx.x;
    if (bx < 2048) {
        __shared__ float tt[32][33];
        const int hw0 = (bx & 31) * 32;
        const int d0  = ((bx >> 5) & 7) * 32;
        const int b   = bx >> 8;
        const int tx = threadIdx.x & 31, ty = threadIdx.x >> 5;
#pragma unroll
        for (int i = 0; i < 4; i++) {
            const int d = d0 + ty + 8 * i;
            tt[ty + 8 * i][tx] = z[(b * 256 + d) * 1024 + hw0 + tx];
        }
        __syncthreads();
#pragma unroll
        for (int i = 0; i < 4; i++) {
            const int hw = hw0 + ty + 8 * i;
            const float v = tt[tx][ty + 8 * i];
            const size_t o = (size_t)(b * 1024 + hw) * DIM + d0 + tx;
            zf[o] = v;
            zb[o] = f2bf(v);
        }
    } else if (bx < 6144) {
        const int s = bx - 2048;
        const int wave = threadIdx.x >> 6, lane = threadIdx.x & 63;
        const int row = s * 4 + wave;
        const float4 v = *(const float4*)(emb + (size_t)row * DIM + lane * 4);
        ushort4 o;
        o.x = f2bf(v.x); o.y = f2bf(v.y); o.z = f2bf(v.z); o.w = f2bf(v.w);
        *(ushort4*)(eb + (size_t)row * DIM + lane * 4) = o;
        float ss = v.x * v.x + v.y * v.y + v.z * v.z + v.w * v.w;
#pragma unroll
        for (int m = 1; m < 64; m <<= 1) ss += __shfl_xor(ss, m, 64);
        if (lane == 0) enorm[row] = ss;
    } else {
        if (threadIdx.x == 0) out_loss[0] = 0.f;
    }
}

// ---------------- bf16 MFMA scoring: 64-row A in LDS (swizzled), B from L2 ----------------
// LDS exactly 32 KB (epilogue staging aliases As) -> up to 5 blocks/CU at VGPR<=96.
// __launch_bounds__(256,4): VGPR cap 128 (NOT 5 — that forced a 48-VGPR spill, R13).
// Group g = by*16 + wc*4 + (m15>>2): codes by*256 + wc*64 + ct*16 + (m15>>2)*4 + l
__global__ __launch_bounds__(256, 4) void k_score(
        const unsigned short* __restrict__ zb, const unsigned short* __restrict__ eb,
        const float* __restrict__ enorm, unsigned short* __restrict__ pvalh) {
    __shared__ unsigned short As[64 * 256];   // 32 KB; reused as sm[64*16] in epilogue
    const int rx = blockIdx.x & 127;
    const int by = blockIdx.x >> 7;
    const int row0 = rx * 64;
    const int col0 = by * 256;
    const int t = threadIdx.x;
    const int lane = t & 63, wc = t >> 6;
    const int q = lane >> 4, m15 = lane & 15;

#pragma unroll
    for (int j = 0; j < 8; j++) {
        const int id = j * 256 + t;
        const int r = id >> 5, sl = id & 31;
        const int c = sl ^ (r & 15);
        __builtin_amdgcn_global_load_lds(
            (const __attribute__((address_space(1))) void*)(zb + (size_t)(row0 + r) * DIM + c * 8),
            (__attribute__((address_space(3))) void*)((char*)As + id * 16), 16, 0, 0);
    }
    __syncthreads();

    f4v acc[4][4];
#pragma unroll
    for (int rt = 0; rt < 4; rt++)
#pragma unroll
        for (int ct = 0; ct < 4; ct++) acc[rt][ct] = (f4v){0.f, 0.f, 0.f, 0.f};

    const unsigned short* brow = eb + (size_t)(col0 + wc * 64 + m15) * DIM + q * 8;

#pragma unroll
    for (int kk = 0; kk < 8; kk++) {
        bf8v af[4], bfv[4];
#pragma unroll
        for (int rt = 0; rt < 4; rt++) {
            const int r = rt * 16 + m15;
            const int slot = (kk * 4 + q) ^ m15;
            af[rt] = *(const bf8v*)&As[r * 256 + slot * 8];
        }
#pragma unroll
        for (int ct = 0; ct < 4; ct++)
            bfv[ct] = *(const bf8v*)(brow + (size_t)ct * 16 * DIM + kk * 32);
#pragma unroll
        for (int rt = 0; rt < 4; rt++)
#pragma unroll
            for (int ct = 0; ct < 4; ct++)
                acc[rt][ct] = __builtin_amdgcn_mfma_f32_16x16x32_bf16(af[rt], bfv[ct], acc[rt][ct], 0, 0, 0);
    }

    // compute all group-mins into registers (no LDS use)
    float en_l[4];
#pragma unroll
    for (int ct = 0; ct < 4; ct++) en_l[ct] = enorm[col0 + wc * 64 + ct * 16 + m15];
    float svr[4][4];
#pragma unroll
    for (int rt = 0; rt < 4; rt++) {
#pragma unroll
        for (int j = 0; j < 4; j++) {
            float s = fmaf(-2.f, acc[rt][0][j], en_l[0]);
#pragma unroll
            for (int ct = 1; ct < 4; ct++)
                s = fminf(s, fmaf(-2.f, acc[rt][ct][j], en_l[ct]));
            svr[rt][j] = s;
        }
#pragma unroll
        for (int m = 1; m <= 2; m <<= 1)
#pragma unroll
            for (int j = 0; j < 4; j++)
                svr[rt][j] = fminf(svr[rt][j], __shfl_xor(svr[rt][j], m, 64));
    }

    // epilogue staging: alias As as sm[64][16] (all ds_reads of As are done; barrier first)
    __syncthreads();
    unsigned short* sm = As;
    const int gsl = wc * 4 + (m15 >> 2);
    if ((m15 & 3) == 0) {
#pragma unroll
        for (int rt = 0; rt < 4; rt++) {
            const int rl = rt * 16 + q * 4;
#pragma unroll
            for (int j = 0; j < 4; j++)
                sm[(rl + j) * 16 + gsl] = __half_as_ushort(__float2half_rn(svr[rt][j]));
        }
    }
    __syncthreads();
    if (t < 128) {
        const u32x4 v = *(const u32x4*)&sm[t * 8];
        __builtin_nontemporal_store(v,
            (u32x4*)&pvalh[(size_t)(row0 + (t >> 1)) * 1024 + by * 16 + (t & 1) * 8]);
    }
}

// ---------------- select: wave-per-row flag + exact fp32 rescore + argmin ----------------
__global__ __launch_bounds__(256) void k_select(
        const float* __restrict__ zf, const float* __restrict__ emb,
        const float* __restrict__ enorm, const unsigned short* __restrict__ pvalh,
        int* __restrict__ idxi, float* __restrict__ out_idx) {
    const int w = threadIdx.x >> 6, lane = threadIdx.x & 63;
    const int row = blockIdx.x * 4 + w;
    __shared__ float zs[4][256];
    __shared__ int lcnt[4];
    __shared__ short list[4][256];

    // z row into LDS + row norm (order-safe: enorm < half-ulp(zn) -> uniform grid shift)
    const float4 zr = *(const float4*)(zf + (size_t)row * DIM + lane * 4);
    *(float4*)&zs[w][lane * 4] = zr;
    float zn = zr.x * zr.x + zr.y * zr.y + zr.z * zr.z + zr.w * zr.w;
#pragma unroll
    for (int m = 1; m < 64; m <<= 1) zn += __shfl_xor(zn, m, 64);
    if (lane == 0) lcnt[w] = 0;

    // group-mins: 16 halves per lane
    const unsigned short* p = pvalh + (size_t)row * 1024;
    const u32x4 u0 = __builtin_nontemporal_load((const u32x4*)(p + lane * 8));
    const u32x4 u1 = __builtin_nontemporal_load((const u32x4*)(p + 512 + lane * 8));
    const __half* h0 = (const __half*)&u0;
    const __half* h1 = (const __half*)&u1;
    float v[16];
    float mn = 3.0e38f;
#pragma unroll
    for (int k = 0; k < 8; k++) {
        v[k] = __half2float(h0[k]);
        v[8 + k] = __half2float(h1[k]);
        mn = fminf(mn, fminf(v[k], v[8 + k]));
    }
#pragma unroll
    for (int m = 1; m < 64; m <<= 1) mn = fminf(mn, __shfl_xor(mn, m, 64));
    const float g = mn + MARGIN;
#pragma unroll
    for (int k = 0; k < 8; k++) {
        if (v[k] <= g) {
            const int pos = atomicAdd(&lcnt[w], 1);
            if (pos < 256) list[w][pos] = (short)(lane * 8 + k);
        }
        if (v[8 + k] <= g) {
            const int pos = atomicAdd(&lcnt[w], 1);
            if (pos < 256) list[w][pos] = (short)(512 + lane * 8 + k);
        }
    }
    const int n = min(lcnt[w], 256);

    // exact fp32 rescore: 4 codes in parallel (16 lanes/code), 4 sub-rounds per 16-code group
    const int codei = lane >> 4, lane16 = lane & 15;
    float bv = 3.0e38f;
    int bi = 0x7fffffff;
    const float* zp = &zs[w][lane16 * 16];
    for (int i = 0; i < n; i++) {
        const int gg = list[w][i];
        const int cbase = ((gg >> 4) << 8) + (((gg >> 2) & 3) << 6) + ((gg & 3) << 2);
#pragma unroll
        for (int sub = 0; sub < 4; sub++) {
            const int ci = sub * 4 + codei;
            const int code = cbase + ((ci >> 2) << 4) + (ci & 3);
            const float* ep = emb + (size_t)code * DIM + lane16 * 16;
            float d = 0.f;
#pragma unroll
            for (int k = 0; k < 16; k += 4) {
                const float4 ev = *(const float4*)(ep + k);
                const float4 zv4 = *(const float4*)(zp + k);
                d = fmaf(zv4.x, ev.x, d);
                d = fmaf(zv4.y, ev.y, d);
                d = fmaf(zv4.z, ev.z, d);
                d = fmaf(zv4.w, ev.w, d);
            }
#pragma unroll
            for (int m = 1; m <= 8; m <<= 1) d += __shfl_xor(d, m, 64);
            if (lane16 == 0) {
                const float tt = zn + enorm[code];
                const float s = tt - 2.0f * d;   // exact fp32 semantics
                if (s < bv || (s == bv && code < bi)) { bv = s; bi = code; }
            }
        }
    }
    // combine the 4 writer lanes (others hold +inf)
#pragma unroll
    for (int m = 1; m < 64; m <<= 1) {
        const float ov = __shfl_xor(bv, m, 64);
        const int oi = __shfl_xor(bi, m, 64);
        if (ov < bv || (ov == bv && oi < bi)) { bv = ov; bi = oi; }
    }
    if (lane == 0) {
        idxi[row] = bi;
        out_idx[row] = (float)bi;
    }
}

// ---------------- gather z_q (NCHW) + fused loss (atomicAdd) ----------------
__global__ __launch_bounds__(256) void k_gather(const float* __restrict__ emb,
                                                const float* __restrict__ zf,
                                                const int* __restrict__ idxi,
                                                float* __restrict__ zq,
                                                float* __restrict__ out_loss) {
    __shared__ float t[32][33];
    const int hw0 = blockIdx.x * 32;
    const int c0  = blockIdx.y * 32;
    const int b   = blockIdx.z;
    const int tx = threadIdx.x & 31, ty = threadIdx.x >> 5;
    float lsum = 0.f;
#pragma unroll
    for (int i = 0; i < 4; i++) {
        const int hh = ty + 8 * i;
        const int n = b * 1024 + hw0 + hh;
        const int id = idxi[n];
        const float q = emb[(size_t)id * DIM + c0 + tx];
        const float zv = zf[(size_t)n * DIM + c0 + tx];
        const float d = q - zv;
        lsum += d * d;
        t[hh][tx] = q;
    }
    __syncthreads();
#pragma unroll
    for (int i = 0; i < 4; i++) {
        const int c = c0 + ty + 8 * i;
        zq[(size_t)(b * 256 + c) * 1024 + hw0 + tx] = t[tx][ty + 8 * i];
    }
#pragma unroll
    for (int m = 1; m < 64; m <<= 1) lsum += __shfl_xor(lsum, m, 64);
    __shared__ float wsum[4];
    const int lane = threadIdx.x & 63, w = threadIdx.x >> 6;
    if (lane == 0) wsum[w] = lsum;
    __syncthreads();
    if (threadIdx.x == 0) {
        const float total = wsum[0] + wsum[1] + wsum[2] + wsum[3];
        atomicAdd(out_loss, total * (1.25f / 2097152.0f));
    }
}

extern "C" void kernel_launch(void* const* d_in, const int* in_sizes, int n_in,
                              void* d_out, int out_size, void* d_ws, size_t ws_size,
                              hipStream_t stream) {
    const float* z   = (const float*)d_in[0];   // [8,256,32,32]
    const float* emb = (const float*)d_in[1];   // [16384,256]
    float* out = (float*)d_out;
    float* ws  = (float*)d_ws;

    // ws layout (float-slot offsets):
    float*          zf    = ws;                                   // 2,097,152  (8 MB)
    unsigned short* pvalh = (unsigned short*)(ws + 2097152);      // 8M halves  (16 MB)
    unsigned short* zb    = (unsigned short*)(ws + 6291456);      // 2M halves  (4 MB)
    unsigned short* eb    = (unsigned short*)(ws + 7340032);      // 4M halves  (8 MB)
    float*          enorm = ws + 9437184;                         // 16,384
    int*            idxi  = (int*)(ws + 9453568);                 // 8,192
    // total ≈ 37.9 MB

    float* zq       = out;                   // [8,256,32,32] NCHW
    float* out_loss = out + 2097152;         // scalar
    float* out_idx  = out + 2097153;         // [8192] as float32

    k_prep<<<dim3(6145), 256, 0, stream>>>(z, emb, zf, zb, eb, enorm, out_loss);
    k_score<<<dim3(8192), 256, 0, stream>>>(zb, eb, enorm, pvalh);
    k_select<<<dim3(2048), 256, 0, stream>>>(zf, emb, enorm, pvalh, idxi, out_idx);
    k_gather<<<dim3(32, 8, 8), 256, 0, stream>>>(emb, zf, idxi, zq, out_loss);
}

// Round 15
// 277.295 us; speedup vs baseline: 1.5270x; 1.0156x over previous
//
#include <hip/hip_runtime.h>
#include <hip/hip_fp16.h>

#define DIM 256
#define MARGIN 2.25e-4f

typedef __bf16 bf8v __attribute__((ext_vector_type(8)));
typedef float f4v __attribute__((ext_vector_type(4)));
typedef unsigned int u32x4 __attribute__((ext_vector_type(4)));

__device__ inline unsigned short f2bf(float x) {
    unsigned u = __float_as_uint(x);
    u += 0x7fffu + ((u >> 16) & 1u);   // RNE
    return (unsigned short)(u >> 16);
}

// ---------------- fused prep ----------------
__global__ __launch_bounds__(256) void k_prep(const float* __restrict__ z,
                                              const float* __restrict__ emb,
                                              float* __restrict__ zf,
                                              unsigned short* __restrict__ zb,
                                              unsigned short* __restrict__ eb,
                                              float* __restrict__ enorm,
                                              float* __restrict__ out_loss) {
    const int bx = blockIdx.x;
    if (bx < 2048) {
        __shared__ float tt[32][33];
        const int hw0 = (bx & 31) * 32;
        const int d0  = ((bx >> 5) & 7) * 32;
        const int b   = bx >> 8;
        const int tx = threadIdx.x & 31, ty = threadIdx.x >> 5;
#pragma unroll
        for (int i = 0; i < 4; i++) {
            const int d = d0 + ty + 8 * i;
            tt[ty + 8 * i][tx] = z[(b * 256 + d) * 1024 + hw0 + tx];
        }
        __syncthreads();
#pragma unroll
        for (int i = 0; i < 4; i++) {
            const int hw = hw0 + ty + 8 * i;
            const float v = tt[tx][ty + 8 * i];
            const size_t o = (size_t)(b * 1024 + hw) * DIM + d0 + tx;
            zf[o] = v;
            zb[o] = f2bf(v);
        }
    } else if (bx < 6144) {
        const int s = bx - 2048;
        const int wave = threadIdx.x >> 6, lane = threadIdx.x & 63;
        const int row = s * 4 + wave;
        const float4 v = *(const float4*)(emb + (size_t)row * DIM + lane * 4);
        ushort4 o;
        o.x = f2bf(v.x); o.y = f2bf(v.y); o.z = f2bf(v.z); o.w = f2bf(v.w);
        *(ushort4*)(eb + (size_t)row * DIM + lane * 4) = o;
        float ss = v.x * v.x + v.y * v.y + v.z * v.z + v.w * v.w;
#pragma unroll
        for (int m = 1; m < 64; m <<= 1) ss += __shfl_xor(ss, m, 64);
        if (lane == 0) enorm[row] = ss;
    } else {
        if (threadIdx.x == 0) out_loss[0] = 0.f;
    }
}

// ---------------- bf16 MFMA scoring: 64-row A in LDS (swizzled), B from XCD-pinned L2 ----------
// XCD swizzle: blockIdx->XCD is round-robin mod 8 [m09], so by-low = blockIdx&7 pins each
// XCD to column-slices by = xcd (mod 8): live B working set per XCD-L2 ~1-2 MB (fits 4 MB).
// Group g = by*16 + wc*4 + (m15>>2): codes by*256 + wc*64 + ct*16 + (m15>>2)*4 + l
__global__ __launch_bounds__(256, 4) void k_score(
        const unsigned short* __restrict__ zb, const unsigned short* __restrict__ eb,
        const float* __restrict__ enorm, unsigned short* __restrict__ pvalh) {
    __shared__ unsigned short As[64 * 256];   // 32 KB; reused as sm[64*16] in epilogue
    const int by = (blockIdx.x & 7) | ((blockIdx.x >> 10) << 3);
    const int rx = (blockIdx.x >> 3) & 127;
    const int row0 = rx * 64;
    const int col0 = by * 256;
    const int t = threadIdx.x;
    const int lane = t & 63, wc = t >> 6;
    const int q = lane >> 4, m15 = lane & 15;

#pragma unroll
    for (int j = 0; j < 8; j++) {
        const int id = j * 256 + t;
        const int r = id >> 5, sl = id & 31;
        const int c = sl ^ (r & 15);
        __builtin_amdgcn_global_load_lds(
            (const __attribute__((address_space(1))) void*)(zb + (size_t)(row0 + r) * DIM + c * 8),
            (__attribute__((address_space(3))) void*)((char*)As + id * 16), 16, 0, 0);
    }
    __syncthreads();

    f4v acc[4][4];
#pragma unroll
    for (int rt = 0; rt < 4; rt++)
#pragma unroll
        for (int ct = 0; ct < 4; ct++) acc[rt][ct] = (f4v){0.f, 0.f, 0.f, 0.f};

    const unsigned short* brow = eb + (size_t)(col0 + wc * 64 + m15) * DIM + q * 8;

#pragma unroll
    for (int kk = 0; kk < 8; kk++) {
        bf8v af[4], bfv[4];
#pragma unroll
        for (int rt = 0; rt < 4; rt++) {
            const int r = rt * 16 + m15;
            const int slot = (kk * 4 + q) ^ m15;
            af[rt] = *(const bf8v*)&As[r * 256 + slot * 8];
        }
#pragma unroll
        for (int ct = 0; ct < 4; ct++)
            bfv[ct] = *(const bf8v*)(brow + (size_t)ct * 16 * DIM + kk * 32);
#pragma unroll
        for (int rt = 0; rt < 4; rt++)
#pragma unroll
            for (int ct = 0; ct < 4; ct++)
                acc[rt][ct] = __builtin_amdgcn_mfma_f32_16x16x32_bf16(af[rt], bfv[ct], acc[rt][ct], 0, 0, 0);
    }

    float en_l[4];
#pragma unroll
    for (int ct = 0; ct < 4; ct++) en_l[ct] = enorm[col0 + wc * 64 + ct * 16 + m15];
    float svr[4][4];
#pragma unroll
    for (int rt = 0; rt < 4; rt++) {
#pragma unroll
        for (int j = 0; j < 4; j++) {
            float s = fmaf(-2.f, acc[rt][0][j], en_l[0]);
#pragma unroll
            for (int ct = 1; ct < 4; ct++)
                s = fminf(s, fmaf(-2.f, acc[rt][ct][j], en_l[ct]));
            svr[rt][j] = s;
        }
#pragma unroll
        for (int m = 1; m <= 2; m <<= 1)
#pragma unroll
            for (int j = 0; j < 4; j++)
                svr[rt][j] = fminf(svr[rt][j], __shfl_xor(svr[rt][j], m, 64));
    }

    __syncthreads();
    unsigned short* sm = As;
    const int gsl = wc * 4 + (m15 >> 2);
    if ((m15 & 3) == 0) {
#pragma unroll
        for (int rt = 0; rt < 4; rt++) {
            const int rl = rt * 16 + q * 4;
#pragma unroll
            for (int j = 0; j < 4; j++)
                sm[(rl + j) * 16 + gsl] = __half_as_ushort(__float2half_rn(svr[rt][j]));
        }
    }
    __syncthreads();
    if (t < 128) {
        const u32x4 v = *(const u32x4*)&sm[t * 8];
        __builtin_nontemporal_store(v,
            (u32x4*)&pvalh[(size_t)(row0 + (t >> 1)) * 1024 + by * 16 + (t & 1) * 8]);
    }
}

// ---------------- select: flag + exact fp32 rescore + argmin + zq write + loss (fused) ----------
__global__ __launch_bounds__(256) void k_select(
        const float* __restrict__ zf, const float* __restrict__ emb,
        const float* __restrict__ enorm, const unsigned short* __restrict__ pvalh,
        float* __restrict__ zq, float* __restrict__ out_idx,
        float* __restrict__ out_loss) {
    const int w = threadIdx.x >> 6, lane = threadIdx.x & 63;
    const int row = blockIdx.x * 4 + w;
    __shared__ float zs[4][256];
    __shared__ int lcnt[4];
    __shared__ short list[4][256];
    __shared__ float wloss[4];

    // z row into LDS + row norm (order-safe: enorm < half-ulp(zn) -> uniform grid shift)
    const float4 zr = *(const float4*)(zf + (size_t)row * DIM + lane * 4);
    *(float4*)&zs[w][lane * 4] = zr;
    float zn = zr.x * zr.x + zr.y * zr.y + zr.z * zr.z + zr.w * zr.w;
#pragma unroll
    for (int m = 1; m < 64; m <<= 1) zn += __shfl_xor(zn, m, 64);
    if (lane == 0) lcnt[w] = 0;

    // group-mins: 16 halves per lane
    const unsigned short* p = pvalh + (size_t)row * 1024;
    const u32x4 u0 = __builtin_nontemporal_load((const u32x4*)(p + lane * 8));
    const u32x4 u1 = __builtin_nontemporal_load((const u32x4*)(p + 512 + lane * 8));
    const __half* h0 = (const __half*)&u0;
    const __half* h1 = (const __half*)&u1;
    float v[16];
    float mn = 3.0e38f;
#pragma unroll
    for (int k = 0; k < 8; k++) {
        v[k] = __half2float(h0[k]);
        v[8 + k] = __half2float(h1[k]);
        mn = fminf(mn, fminf(v[k], v[8 + k]));
    }
#pragma unroll
    for (int m = 1; m < 64; m <<= 1) mn = fminf(mn, __shfl_xor(mn, m, 64));
    const float g = mn + MARGIN;
#pragma unroll
    for (int k = 0; k < 8; k++) {
        if (v[k] <= g) {
            const int pos = atomicAdd(&lcnt[w], 1);
            if (pos < 256) list[w][pos] = (short)(lane * 8 + k);
        }
        if (v[8 + k] <= g) {
            const int pos = atomicAdd(&lcnt[w], 1);
            if (pos < 256) list[w][pos] = (short)(512 + lane * 8 + k);
        }
    }
    const int n = min(lcnt[w], 256);

    // exact fp32 rescore: 4 codes in parallel (16 lanes/code), 4 sub-rounds per 16-code group
    const int codei = lane >> 4, lane16 = lane & 15;
    float bv = 3.0e38f;
    int bi = 0x7fffffff;
    const float* zp = &zs[w][lane16 * 16];
    for (int i = 0; i < n; i++) {
        const int gg = list[w][i];
        const int cbase = ((gg >> 4) << 8) + (((gg >> 2) & 3) << 6) + ((gg & 3) << 2);
#pragma unroll
        for (int sub = 0; sub < 4; sub++) {
            const int ci = sub * 4 + codei;
            const int code = cbase + ((ci >> 2) << 4) + (ci & 3);
            const float* ep = emb + (size_t)code * DIM + lane16 * 16;
            float d = 0.f;
#pragma unroll
            for (int k = 0; k < 16; k += 4) {
                const float4 ev = *(const float4*)(ep + k);
                const float4 zv4 = *(const float4*)(zp + k);
                d = fmaf(zv4.x, ev.x, d);
                d = fmaf(zv4.y, ev.y, d);
                d = fmaf(zv4.z, ev.z, d);
                d = fmaf(zv4.w, ev.w, d);
            }
#pragma unroll
            for (int m = 1; m <= 8; m <<= 1) d += __shfl_xor(d, m, 64);
            if (lane16 == 0) {
                const float tt = zn + enorm[code];
                const float s = tt - 2.0f * d;   // exact fp32 semantics
                if (s < bv || (s == bv && code < bi)) { bv = s; bi = code; }
            }
        }
    }
    // combine the 4 writer lanes (others hold +inf)
#pragma unroll
    for (int m = 1; m < 64; m <<= 1) {
        const float ov = __shfl_xor(bv, m, 64);
        const int oi = __shfl_xor(bi, m, 64);
        if (ov < bv || (ov == bv && oi < bi)) { bv = ov; bi = oi; }
    }
    bi = __shfl(bi, 0, 64);

    // fused epilogue: winner row -> loss + z_q (NCHW scatter; 4-consecutive-hw rows/block
    // land in the same 64B lines across waves -> L2 merges)
    const int b = row >> 10, hw = row & 1023;
    const float4 q4 = *(const float4*)(emb + (size_t)bi * DIM + lane * 4);
    const float4 z4 = *(const float4*)&zs[w][lane * 4];
    const float d0 = q4.x - z4.x, d1 = q4.y - z4.y, d2 = q4.z - z4.z, d3 = q4.w - z4.w;
    float lsum = d0 * d0 + d1 * d1 + d2 * d2 + d3 * d3;
    float* zqp = zq + ((size_t)b * 256 + lane * 4) * 1024 + hw;
    zqp[0] = q4.x; zqp[1024] = q4.y; zqp[2048] = q4.z; zqp[3072] = q4.w;
#pragma unroll
    for (int m = 1; m < 64; m <<= 1) lsum += __shfl_xor(lsum, m, 64);
    if (lane == 0) {
        out_idx[row] = (float)bi;
        wloss[w] = lsum;
    }
    __syncthreads();
    if (threadIdx.x == 0) {
        const float total = wloss[0] + wloss[1] + wloss[2] + wloss[3];
        atomicAdd(out_loss, total * (1.25f / 2097152.0f));
    }
}

extern "C" void kernel_launch(void* const* d_in, const int* in_sizes, int n_in,
                              void* d_out, int out_size, void* d_ws, size_t ws_size,
                              hipStream_t stream) {
    const float* z   = (const float*)d_in[0];   // [8,256,32,32]
    const float* emb = (const float*)d_in[1];   // [16384,256]
    float* out = (float*)d_out;
    float* ws  = (float*)d_ws;

    // ws layout (float-slot offsets):
    float*          zf    = ws;                                   // 2,097,152  (8 MB)
    unsigned short* pvalh = (unsigned short*)(ws + 2097152);      // 8M halves  (16 MB)
    unsigned short* zb    = (unsigned short*)(ws + 6291456);      // 2M halves  (4 MB)
    unsigned short* eb    = (unsigned short*)(ws + 7340032);      // 4M halves  (8 MB)
    float*          enorm = ws + 9437184;                         // 16,384
    // total ≈ 37.8 MB

    float* zq       = out;                   // [8,256,32,32] NCHW
    float* out_loss = out + 2097152;         // scalar
    float* out_idx  = out + 2097153;         // [8192] as float32

    k_prep<<<dim3(6145), 256, 0, stream>>>(z, emb, zf, zb, eb, enorm, out_loss);
    k_score<<<dim3(8192), 256, 0, stream>>>(zb, eb, enorm, pvalh);
    k_select<<<dim3(2048), 256, 0, stream>>>(zf, emb, enorm, pvalh, zq, out_idx, out_loss);
}